// Round 2
// baseline (2649.275 us; speedup 1.0000x reference)
//
#include <hip/hip_runtime.h>
#include <hip/hip_bf16.h>

#define NN 100000
#define EE 500000
#define BB 4096
#define HC 128

// ---- Combined 4-plane GEMM: stages 16 input rows to LDS once, computes q,k,v,s.
// S may alias `in` (layers 2/3): safe because each row is staged by exactly the
// block that overwrites it, before the overwrite.
__global__ __launch_bounds__(256) void gemm_all(
    const float* __restrict__ in, int K,
    const float* __restrict__ Wq, const float* __restrict__ Wk,
    const float* __restrict__ Wv, const float* __restrict__ Wsk,
    const float* __restrict__ bq, const float* __restrict__ bk,
    const float* __restrict__ bv, const float* __restrict__ bs,
    float* __restrict__ Q, float* __restrict__ Kp,
    float* __restrict__ V, float* __restrict__ S)
{
    __shared__ float xs[16 * 128];
    const int tid = threadIdx.x;
    const int rows0 = blockIdx.x * 16;
    const int total = 16 * K;
    const float* src = in + (size_t)rows0 * K;
    for (int i = tid * 4; i < total; i += 1024)
        *(float4*)(xs + i) = *(const float4*)(src + i);
    __syncthreads();

    const int col = tid & 127;
    const int rg = tid >> 7;               // 0/1 -> rows rg*8..rg*8+7
    const float* xr = xs + rg * 8 * K;

    const float* Warr[4] = {Wq, Kp ? Wk : Wk, Wv, Wsk};
    const float* barr[4] = {bq, bk, bv, bs};
    float* Oarr[4] = {Q, Kp, V, S};

#pragma unroll
    for (int p = 0; p < 4; p++) {
        const float* W = Warr[p];
        float acc[8];
        const float b = barr[p][col];
#pragma unroll
        for (int r = 0; r < 8; r++) acc[r] = b;
        for (int k = 0; k < K; k += 4) {
            const float w0 = W[(k + 0) * 128 + col];
            const float w1 = W[(k + 1) * 128 + col];
            const float w2 = W[(k + 2) * 128 + col];
            const float w3 = W[(k + 3) * 128 + col];
#pragma unroll
            for (int r = 0; r < 8; r++) {
                const float4 x4 = *(const float4*)(xr + r * K + k);
                acc[r] += x4.x * w0 + x4.y * w1 + x4.z * w2 + x4.w * w3;
            }
        }
        float* o = Oarr[p] + (size_t)(rows0 + rg * 8) * HC + col;
#pragma unroll
        for (int r = 0; r < 8; r++) o[r * HC] = acc[r];
    }
}

// ---- Edge pass 1: alpha = exp(q[dst].(k[src]+e)/sqrt(32)) per head; asum scatter.
__global__ __launch_bounds__(256) void edge_p1(
    const int* __restrict__ ei, const float* __restrict__ ea,
    const float* __restrict__ We,
    const float* __restrict__ Q, const float* __restrict__ Kp,
    float* __restrict__ alpha_buf, float* __restrict__ asum)
{
    __shared__ float wes[512];
    const int tid = threadIdx.x;
    for (int i = tid; i < 512; i += 256) wes[i] = We[i];
    __syncthreads();

    const int lane = tid & 63;
    const int e = blockIdx.x * 4 + (tid >> 6);
    const int src = ei[e];
    const int dst = ei[EE + e];
    const float4 a4 = *(const float4*)(ea + (size_t)e * 4);
    const int c = lane * 2;
    const float e0 = a4.x * wes[c]     + a4.y * wes[128 + c]     + a4.z * wes[256 + c]     + a4.w * wes[384 + c];
    const float e1 = a4.x * wes[c + 1] + a4.y * wes[128 + c + 1] + a4.z * wes[256 + c + 1] + a4.w * wes[384 + c + 1];

    const float2 q2 = *(const float2*)(Q + (size_t)dst * HC + c);
    const float2 k2 = *(const float2*)(Kp + (size_t)src * HC + c);
    float part = q2.x * (k2.x + e0) + q2.y * (k2.y + e1);
    part += __shfl_xor(part, 1);
    part += __shfl_xor(part, 2);
    part += __shfl_xor(part, 4);
    part += __shfl_xor(part, 8);
    const float al = expf(part * 0.17677669529663687f);  // 1/sqrt(32)
    if ((lane & 15) == 0) {
        alpha_buf[(size_t)e * 4 + (lane >> 4)] = al;
        atomicAdd(asum + (size_t)dst * 4 + (lane >> 4), al);
    }
}

// ---- Edge pass 2: scatter (v[src]+e) * alpha/asum[dst] onto H (holds skip).
__global__ __launch_bounds__(256) void edge_p2(
    const int* __restrict__ ei, const float* __restrict__ ea,
    const float* __restrict__ We,
    const float* __restrict__ V, const float* __restrict__ alpha_buf,
    const float* __restrict__ asum, float* __restrict__ H)
{
    __shared__ float wes[512];
    const int tid = threadIdx.x;
    for (int i = tid; i < 512; i += 256) wes[i] = We[i];
    __syncthreads();

    const int lane = tid & 63;
    const int e = blockIdx.x * 4 + (tid >> 6);
    const int src = ei[e];
    const int dst = ei[EE + e];
    const float4 a4 = *(const float4*)(ea + (size_t)e * 4);
    const int c = lane * 2;
    const float e0 = a4.x * wes[c]     + a4.y * wes[128 + c]     + a4.z * wes[256 + c]     + a4.w * wes[384 + c];
    const float e1 = a4.x * wes[c + 1] + a4.y * wes[128 + c + 1] + a4.z * wes[256 + c + 1] + a4.w * wes[384 + c + 1];

    const int h = lane >> 4;
    const float al = alpha_buf[(size_t)e * 4 + h];
    const float w = al / (asum[(size_t)dst * 4 + h] + 1e-16f);
    const float2 v2 = *(const float2*)(V + (size_t)src * HC + c);
    atomicAdd(H + (size_t)dst * HC + c,     (v2.x + e0) * w);
    atomicAdd(H + (size_t)dst * HC + c + 1, (v2.y + e1) * w);
}

__global__ __launch_bounds__(256) void relu_k(float* __restrict__ H)
{
    const int g = blockIdx.x * 256 + threadIdx.x;
    if (g < NN * HC) H[g] = fmaxf(H[g], 0.f);
}

__global__ __launch_bounds__(256) void pool_scatter(
    const float* __restrict__ h, const int* __restrict__ batch,
    float* __restrict__ pooled, float* __restrict__ cnt)
{
    const int gid = blockIdx.x * 256 + threadIdx.x;
    if (gid >= NN * HC) return;
    const int n = gid >> 7;
    const int hc = gid & 127;
    const int b = batch[n];
    atomicAdd(pooled + (size_t)b * HC + hc, h[gid]);
    if (hc == 0) atomicAdd(cnt + b, 1.0f);
}

__global__ __launch_bounds__(256) void head_k(
    const float* __restrict__ pooled, const float* __restrict__ cnt,
    const int* __restrict__ rt, const float* __restrict__ hW,
    const float* __restrict__ hb, float* __restrict__ out)
{
    const int lane = threadIdx.x & 63;
    const int b = blockIdx.x * 4 + (threadIdx.x >> 6);
    if (b >= BB) return;
    const int t = rt[b];
    const int c = lane * 2;
    const float2 p2 = *(const float2*)(pooled + (size_t)b * HC + c);
    const float2 w2 = *(const float2*)(hW + (size_t)t * HC + c);
    float part = p2.x * w2.x + p2.y * w2.y;
    part += __shfl_xor(part, 1);
    part += __shfl_xor(part, 2);
    part += __shfl_xor(part, 4);
    part += __shfl_xor(part, 8);
    part += __shfl_xor(part, 16);
    part += __shfl_xor(part, 32);
    if (lane == 0) out[b] = part / fmaxf(cnt[b], 1.0f) + hb[t];
}

extern "C" void kernel_launch(void* const* d_in, const int* in_sizes, int n_in,
                              void* d_out, int out_size, void* d_ws, size_t ws_size,
                              hipStream_t stream) {
    const float* x      = (const float*)d_in[0];
    const int*   ei     = (const int*)d_in[1];
    const float* ea     = (const float*)d_in[2];
    const int*   batch  = (const int*)d_in[3];
    const int*   rt     = (const int*)d_in[4];

    // workspace layout (floats) — total 54,128,384 floats = 216.5 MB
    float* ws     = (float*)d_ws;
    float* Q      = ws;                       // 12,800,000
    float* Kp     = ws + 12800000;            // 12,800,000
    float* V      = ws + 25600000;            // 12,800,000
    float* Hbuf   = ws + 38400000;            // 12,800,000 (skip + msg accumulator = layer output)
    float* alphab = ws + 51200000;            //  2,000,000 (E*4)
    float* asum   = ws + 53200000;            //    400,000 (N*4)
    float* pooled = ws + 53600000;            //    524,288 (B*128)
    float* cnt    = ws + 54124288;            //      4,096

    for (int l = 0; l < 3; l++) {
        const float* in = (l == 0) ? x : Hbuf;
        const int K = (l == 0) ? 64 : 128;
        const float *Wq, *Wk, *Wv, *Wsk, *bq, *bk, *bv, *bs, *We;
        if (l == 0) {
            Wq = (const float*)d_in[5];  bq = (const float*)d_in[6];
            Wk = (const float*)d_in[7];  bk = (const float*)d_in[8];
            Wv = (const float*)d_in[9];  bv = (const float*)d_in[10];
            We = (const float*)d_in[11];
            Wsk= (const float*)d_in[12]; bs = (const float*)d_in[13];
        } else {
            const int j = l - 1;
            Wq = (const float*)d_in[14] + (size_t)j * HC * HC;  bq = (const float*)d_in[15] + j * HC;
            Wk = (const float*)d_in[16] + (size_t)j * HC * HC;  bk = (const float*)d_in[17] + j * HC;
            Wv = (const float*)d_in[18] + (size_t)j * HC * HC;  bv = (const float*)d_in[19] + j * HC;
            We = (const float*)d_in[20] + (size_t)j * 4 * HC;
            Wsk= (const float*)d_in[21] + (size_t)j * HC * HC;  bs = (const float*)d_in[22] + j * HC;
        }

        gemm_all<<<NN / 16, 256, 0, stream>>>(in, K, Wq, Wk, Wv, Wsk, bq, bk, bv, bs,
                                              Q, Kp, V, Hbuf);
        hipMemsetAsync(asum, 0, (size_t)NN * 4 * sizeof(float), stream);
        edge_p1<<<EE / 4, 256, 0, stream>>>(ei, ea, We, Q, Kp, alphab, asum);
        edge_p2<<<EE / 4, 256, 0, stream>>>(ei, ea, We, V, alphab, asum, Hbuf);
        if (l < 2) relu_k<<<(NN * HC) / 256, 256, 0, stream>>>(Hbuf);
    }

    hipMemsetAsync(pooled, 0, (size_t)(BB * HC + BB) * sizeof(float), stream);
    pool_scatter<<<(NN * HC) / 256, 256, 0, stream>>>(Hbuf, batch, pooled, cnt);
    head_k<<<BB / 4, 256, 0, stream>>>(pooled, cnt, rt,
        (const float*)d_in[23], (const float*)d_in[24], (float*)d_out);
}

// Round 3
// 1821.856 us; speedup vs baseline: 1.4542x; 1.4542x over previous
//
#include <hip/hip_runtime.h>
#include <hip/hip_bf16.h>

#define NN 100000
#define EE 500000
#define BB 4096
#define HC 128

// ---- Combined 4-plane GEMM: stages 16 input rows to LDS once, computes q,k,v,s.
// S may alias `in` (layers 2/3): safe because each row is staged by exactly the
// block that overwrites it, before the overwrite.
__global__ __launch_bounds__(256) void gemm_all(
    const float* __restrict__ in, int K,
    const float* __restrict__ Wq, const float* __restrict__ Wk,
    const float* __restrict__ Wv, const float* __restrict__ Wsk,
    const float* __restrict__ bq, const float* __restrict__ bk,
    const float* __restrict__ bv, const float* __restrict__ bs,
    float* __restrict__ Q, float* __restrict__ Kp,
    float* __restrict__ V, float* __restrict__ S)
{
    __shared__ float xs[16 * 128];
    const int tid = threadIdx.x;
    const int rows0 = blockIdx.x * 16;
    const int total = 16 * K;
    const float* src = in + (size_t)rows0 * K;
    for (int i = tid * 4; i < total; i += 1024)
        *(float4*)(xs + i) = *(const float4*)(src + i);
    __syncthreads();

    const int col = tid & 127;
    const int rg = tid >> 7;               // 0/1 -> rows rg*8..rg*8+7
    const float* xr = xs + rg * 8 * K;

    const float* Warr[4] = {Wq, Wk, Wv, Wsk};
    const float* barr[4] = {bq, bk, bv, bs};
    float* Oarr[4] = {Q, Kp, V, S};

#pragma unroll
    for (int p = 0; p < 4; p++) {
        const float* W = Warr[p];
        float acc[8];
        const float b = barr[p][col];
#pragma unroll
        for (int r = 0; r < 8; r++) acc[r] = b;
        for (int k = 0; k < K; k += 4) {
            const float w0 = W[(k + 0) * 128 + col];
            const float w1 = W[(k + 1) * 128 + col];
            const float w2 = W[(k + 2) * 128 + col];
            const float w3 = W[(k + 3) * 128 + col];
#pragma unroll
            for (int r = 0; r < 8; r++) {
                const float4 x4 = *(const float4*)(xr + r * K + k);
                acc[r] += x4.x * w0 + x4.y * w1 + x4.z * w2 + x4.w * w3;
            }
        }
        float* o = Oarr[p] + (size_t)(rows0 + rg * 8) * HC + col;
#pragma unroll
        for (int r = 0; r < 8; r++) o[r * HC] = acc[r];
    }
}

// ---- CSR build: degree histogram -> exclusive scan -> bucket scatter --------
__global__ __launch_bounds__(256) void deg_k(const int* __restrict__ ei, int* __restrict__ deg)
{
    const int e = blockIdx.x * 256 + threadIdx.x;
    if (e < EE) atomicAdd(&deg[ei[EE + e]], 1);
}

__global__ __launch_bounds__(256) void scan_k(const int* __restrict__ deg,
                                              int* __restrict__ off,
                                              int* __restrict__ cursor)
{
    __shared__ int buf[256];
    __shared__ int carry_s;
    if (threadIdx.x == 0) carry_s = 0;
    __syncthreads();
    for (int base = 0; base < NN; base += 256) {
        const int i = base + threadIdx.x;
        const int v = (i < NN) ? deg[i] : 0;
        buf[threadIdx.x] = v;
        __syncthreads();
        for (int s = 1; s < 256; s <<= 1) {
            const int t = (threadIdx.x >= s) ? buf[threadIdx.x - s] : 0;
            __syncthreads();
            buf[threadIdx.x] += t;
            __syncthreads();
        }
        const int incl = buf[threadIdx.x];
        const int c = carry_s;
        if (i < NN) {
            off[i] = c + incl - v;
            cursor[i] = c + incl - v;
        }
        __syncthreads();
        if (threadIdx.x == 255) carry_s = c + incl;
        __syncthreads();
    }
    if (threadIdx.x == 0) off[NN] = carry_s;
}

__global__ __launch_bounds__(256) void bucket_k(const int* __restrict__ ei,
                                                int* __restrict__ cursor,
                                                int* __restrict__ eids)
{
    const int e = blockIdx.x * 256 + threadIdx.x;
    if (e < EE) {
        const int d = ei[EE + e];
        const int p = atomicAdd(&cursor[d], 1);
        eids[p] = e;
    }
}

// ---- Fused edge stage: one wave per dst node, gather-based, no atomics. -----
// H holds the skip (x @ Ws + bs); we overwrite with relu(msg/den + skip).
__global__ __launch_bounds__(256) void edge_fused(
    const int* __restrict__ ei, const float* __restrict__ ea,
    const float* __restrict__ We,
    const float* __restrict__ Q, const float* __restrict__ Kp,
    const float* __restrict__ V,
    const int* __restrict__ off, const int* __restrict__ eids,
    float* __restrict__ H, int do_relu)
{
    __shared__ float wes[512];
    for (int i = threadIdx.x; i < 512; i += 256) wes[i] = We[i];
    __syncthreads();

    const int lane = threadIdx.x & 63;
    const int n = blockIdx.x * 4 + (threadIdx.x >> 6);
    const int c = lane * 2;
    const float w00 = wes[c],     w10 = wes[128 + c],     w20 = wes[256 + c],     w30 = wes[384 + c];
    const float w01 = wes[c + 1], w11 = wes[128 + c + 1], w21 = wes[256 + c + 1], w31 = wes[384 + c + 1];

    const int beg = off[n], end = off[n + 1];
    const float2 q2 = *(const float2*)(Q + (size_t)n * HC + c);
    float num0 = 0.f, num1 = 0.f, den = 0.f;

    for (int p = beg; p < end; p++) {
        const int e = eids[p];
        const int src = ei[e];
        const float4 a4 = *(const float4*)(ea + (size_t)e * 4);
        const float e0 = a4.x * w00 + a4.y * w10 + a4.z * w20 + a4.w * w30;
        const float e1 = a4.x * w01 + a4.y * w11 + a4.z * w21 + a4.w * w31;
        const float2 k2 = *(const float2*)(Kp + (size_t)src * HC + c);
        float part = q2.x * (k2.x + e0) + q2.y * (k2.y + e1);
        part += __shfl_xor(part, 1);
        part += __shfl_xor(part, 2);
        part += __shfl_xor(part, 4);
        part += __shfl_xor(part, 8);
        const float al = expf(part * 0.17677669529663687f);  // 1/sqrt(32)
        const float2 v2 = *(const float2*)(V + (size_t)src * HC + c);
        num0 += (v2.x + e0) * al;
        num1 += (v2.y + e1) * al;
        den += al;
    }

    float2* h = (float2*)(H + (size_t)n * HC + c);
    const float2 skip = *h;
    const float inv = 1.f / (den + 1e-16f);
    float o0 = num0 * inv + skip.x;
    float o1 = num1 * inv + skip.y;
    if (do_relu) { o0 = fmaxf(o0, 0.f); o1 = fmaxf(o1, 0.f); }
    *h = make_float2(o0, o1);
}

__global__ __launch_bounds__(256) void pool_scatter(
    const float* __restrict__ h, const int* __restrict__ batch,
    float* __restrict__ pooled, float* __restrict__ cnt)
{
    const int gid = blockIdx.x * 256 + threadIdx.x;
    if (gid >= NN * HC) return;
    const int n = gid >> 7;
    const int hc = gid & 127;
    const int b = batch[n];
    atomicAdd(pooled + (size_t)b * HC + hc, h[gid]);
    if (hc == 0) atomicAdd(cnt + b, 1.0f);
}

__global__ __launch_bounds__(256) void head_k(
    const float* __restrict__ pooled, const float* __restrict__ cnt,
    const int* __restrict__ rt, const float* __restrict__ hW,
    const float* __restrict__ hb, float* __restrict__ out)
{
    const int lane = threadIdx.x & 63;
    const int b = blockIdx.x * 4 + (threadIdx.x >> 6);
    if (b >= BB) return;
    const int t = rt[b];
    const int c = lane * 2;
    const float2 p2 = *(const float2*)(pooled + (size_t)b * HC + c);
    const float2 w2 = *(const float2*)(hW + (size_t)t * HC + c);
    float part = p2.x * w2.x + p2.y * w2.y;
    part += __shfl_xor(part, 1);
    part += __shfl_xor(part, 2);
    part += __shfl_xor(part, 4);
    part += __shfl_xor(part, 8);
    part += __shfl_xor(part, 16);
    part += __shfl_xor(part, 32);
    if (lane == 0) out[b] = part / fmaxf(cnt[b], 1.0f) + hb[t];
}

extern "C" void kernel_launch(void* const* d_in, const int* in_sizes, int n_in,
                              void* d_out, int out_size, void* d_ws, size_t ws_size,
                              hipStream_t stream) {
    const float* x      = (const float*)d_in[0];
    const int*   ei     = (const int*)d_in[1];
    const float* ea     = (const float*)d_in[2];
    const int*   batch  = (const int*)d_in[3];
    const int*   rt     = (const int*)d_in[4];

    // workspace layout (floats/ints) — total ~215 MB
    float* ws     = (float*)d_ws;
    float* Q      = ws;                       // 12,800,000 f
    float* Kp     = ws + 12800000;            // 12,800,000 f
    float* V      = ws + 25600000;            // 12,800,000 f
    float* Hbuf   = ws + 38400000;            // 12,800,000 f (skip + msg = layer output)
    int*   deg    = (int*)(ws + 51200000);    // 100,000 i
    int*   off    = deg + 100000;             // 100,001 i
    int*   cursor = off + 100004;             // 100,000 i
    int*   eids   = cursor + 100000;          // 500,000 i
    float* pooled = (float*)(eids + 500000);  // 524,288 f
    float* cnt    = pooled + 524288;          // 4,096 f

    // ---- CSR build (graph is identical every call; rebuilt because ws is re-poisoned)
    hipMemsetAsync(deg, 0, 100000 * sizeof(int), stream);
    deg_k<<<(EE + 255) / 256, 256, 0, stream>>>(ei, deg);
    scan_k<<<1, 256, 0, stream>>>(deg, off, cursor);
    bucket_k<<<(EE + 255) / 256, 256, 0, stream>>>(ei, cursor, eids);

    for (int l = 0; l < 3; l++) {
        const float* in = (l == 0) ? x : Hbuf;
        const int K = (l == 0) ? 64 : 128;
        const float *Wq, *Wk, *Wv, *Wsk, *bq, *bk, *bv, *bs, *We;
        if (l == 0) {
            Wq = (const float*)d_in[5];  bq = (const float*)d_in[6];
            Wk = (const float*)d_in[7];  bk = (const float*)d_in[8];
            Wv = (const float*)d_in[9];  bv = (const float*)d_in[10];
            We = (const float*)d_in[11];
            Wsk= (const float*)d_in[12]; bs = (const float*)d_in[13];
        } else {
            const int j = l - 1;
            Wq = (const float*)d_in[14] + (size_t)j * HC * HC;  bq = (const float*)d_in[15] + j * HC;
            Wk = (const float*)d_in[16] + (size_t)j * HC * HC;  bk = (const float*)d_in[17] + j * HC;
            Wv = (const float*)d_in[18] + (size_t)j * HC * HC;  bv = (const float*)d_in[19] + j * HC;
            We = (const float*)d_in[20] + (size_t)j * 4 * HC;
            Wsk= (const float*)d_in[21] + (size_t)j * HC * HC;  bs = (const float*)d_in[22] + j * HC;
        }

        gemm_all<<<NN / 16, 256, 0, stream>>>(in, K, Wq, Wk, Wv, Wsk, bq, bk, bv, bs,
                                              Q, Kp, V, Hbuf);
        edge_fused<<<NN / 4, 256, 0, stream>>>(ei, ea, We, Q, Kp, V, off, eids,
                                               Hbuf, l < 2 ? 1 : 0);
    }

    hipMemsetAsync(pooled, 0, (size_t)(BB * HC + BB) * sizeof(float), stream);
    pool_scatter<<<(NN * HC) / 256, 256, 0, stream>>>(Hbuf, batch, pooled, cnt);
    head_k<<<BB / 4, 256, 0, stream>>>(pooled, cnt, rt,
        (const float*)d_in[23], (const float*)d_in[24], (float*)d_out);
}

// Round 4
// 1405.781 us; speedup vs baseline: 1.8846x; 1.2960x over previous
//
#include <hip/hip_runtime.h>
#include <hip/hip_bf16.h>

#define NN 100000
#define EE 500000
#define BB 4096
#define HC 128
#define SCAN_ELEM 1024
#define NSB ((NN + SCAN_ELEM - 1) / SCAN_ELEM)   // 98 blocks

// ---- Combined 4-plane GEMM: stages 16 input rows to LDS once, computes q,k,v,s.
// S may alias `in` (layers 2/3): safe because each row is staged by exactly the
// block that overwrites it, before the overwrite.
__global__ __launch_bounds__(256) void gemm_all(
    const float* __restrict__ in, int K,
    const float* __restrict__ Wq, const float* __restrict__ Wk,
    const float* __restrict__ Wv, const float* __restrict__ Wsk,
    const float* __restrict__ bq, const float* __restrict__ bk,
    const float* __restrict__ bv, const float* __restrict__ bs,
    float* __restrict__ Q, float* __restrict__ Kp,
    float* __restrict__ V, float* __restrict__ S)
{
    __shared__ float xs[16 * 128];
    const int tid = threadIdx.x;
    const int rows0 = blockIdx.x * 16;
    const int total = 16 * K;
    const float* src = in + (size_t)rows0 * K;
    for (int i = tid * 4; i < total; i += 1024)
        *(float4*)(xs + i) = *(const float4*)(src + i);
    __syncthreads();

    const int col = tid & 127;
    const int rg = tid >> 7;               // 0/1 -> rows rg*8..rg*8+7
    const float* xr = xs + rg * 8 * K;

    const float* Warr[4] = {Wq, Wk, Wv, Wsk};
    const float* barr[4] = {bq, bk, bv, bs};
    float* Oarr[4] = {Q, Kp, V, S};

#pragma unroll
    for (int p = 0; p < 4; p++) {
        const float* W = Warr[p];
        float acc[8];
        const float b = barr[p][col];
#pragma unroll
        for (int r = 0; r < 8; r++) acc[r] = b;
        for (int k = 0; k < K; k += 4) {
            const float w0 = W[(k + 0) * 128 + col];
            const float w1 = W[(k + 1) * 128 + col];
            const float w2 = W[(k + 2) * 128 + col];
            const float w3 = W[(k + 3) * 128 + col];
#pragma unroll
            for (int r = 0; r < 8; r++) {
                const float4 x4 = *(const float4*)(xr + r * K + k);
                acc[r] += x4.x * w0 + x4.y * w1 + x4.z * w2 + x4.w * w3;
            }
        }
        float* o = Oarr[p] + (size_t)(rows0 + rg * 8) * HC + col;
#pragma unroll
        for (int r = 0; r < 8; r++) o[r * HC] = acc[r];
    }
}

// ---- CSR build: degree histogram -> hierarchical scan -> bucket scatter -----
__global__ __launch_bounds__(256) void deg_k(const int* __restrict__ ei, int* __restrict__ deg)
{
    const int e = blockIdx.x * 256 + threadIdx.x;
    if (e < EE) atomicAdd(&deg[ei[EE + e]], 1);
}

// 98 blocks, each reduces 1024 elements -> bsum[block]
__global__ __launch_bounds__(256) void scan_part(const int* __restrict__ deg,
                                                 int* __restrict__ bsum)
{
    __shared__ int red[256];
    const int base = blockIdx.x * SCAN_ELEM + threadIdx.x * 4;
    int s = 0;
#pragma unroll
    for (int j = 0; j < 4; j++) { const int i = base + j; if (i < NN) s += deg[i]; }
    red[threadIdx.x] = s;
    __syncthreads();
    for (int st = 128; st > 0; st >>= 1) {
        if (threadIdx.x < st) red[threadIdx.x] += red[threadIdx.x + st];
        __syncthreads();
    }
    if (threadIdx.x == 0) bsum[blockIdx.x] = red[0];
}

// single small block: exclusive scan of the 98 block sums
__global__ __launch_bounds__(128) void scan_top(const int* __restrict__ bsum,
                                                int* __restrict__ boff)
{
    __shared__ int buf[128];
    const int v = (threadIdx.x < NSB) ? bsum[threadIdx.x] : 0;
    buf[threadIdx.x] = v;
    __syncthreads();
    for (int s = 1; s < 128; s <<= 1) {
        const int t = (threadIdx.x >= s) ? buf[threadIdx.x - s] : 0;
        __syncthreads();
        buf[threadIdx.x] += t;
        __syncthreads();
    }
    if (threadIdx.x < NSB) boff[threadIdx.x] = buf[threadIdx.x] - v;
}

// 98 blocks: local scan + block offset -> off/cursor; last block writes off[NN]
__global__ __launch_bounds__(256) void scan_final(const int* __restrict__ deg,
                                                  const int* __restrict__ boff,
                                                  int* __restrict__ off,
                                                  int* __restrict__ cursor)
{
    __shared__ int tsum[256];
    const int base = blockIdx.x * SCAN_ELEM + threadIdx.x * 4;
    int vals[4];
    int s = 0;
#pragma unroll
    for (int j = 0; j < 4; j++) {
        const int i = base + j;
        vals[j] = (i < NN) ? deg[i] : 0;
        s += vals[j];
    }
    tsum[threadIdx.x] = s;
    __syncthreads();
    for (int st = 1; st < 256; st <<= 1) {
        const int t = (threadIdx.x >= st) ? tsum[threadIdx.x - st] : 0;
        __syncthreads();
        tsum[threadIdx.x] += t;
        __syncthreads();
    }
    int ex = boff[blockIdx.x] + tsum[threadIdx.x] - s;
#pragma unroll
    for (int j = 0; j < 4; j++) {
        const int i = base + j;
        if (i < NN) { off[i] = ex; cursor[i] = ex; }
        ex += vals[j];
    }
    if (blockIdx.x == NSB - 1 && threadIdx.x == 255)
        off[NN] = boff[blockIdx.x] + tsum[255];
}

__global__ __launch_bounds__(256) void bucket_k(const int* __restrict__ ei,
                                                int* __restrict__ cursor,
                                                int* __restrict__ eids)
{
    const int e = blockIdx.x * 256 + threadIdx.x;
    if (e < EE) {
        const int d = ei[EE + e];
        const int p = atomicAdd(&cursor[d], 1);
        eids[p] = e;
    }
}

// ---- Fused edge stage: one wave per dst node, gather-based, no atomics. -----
// H holds the skip (x @ Ws + bs); we overwrite with relu(msg/den + skip).
__global__ __launch_bounds__(256) void edge_fused(
    const int* __restrict__ ei, const float* __restrict__ ea,
    const float* __restrict__ We,
    const float* __restrict__ Q, const float* __restrict__ Kp,
    const float* __restrict__ V,
    const int* __restrict__ off, const int* __restrict__ eids,
    float* __restrict__ H, int do_relu)
{
    __shared__ float wes[512];
    for (int i = threadIdx.x; i < 512; i += 256) wes[i] = We[i];
    __syncthreads();

    const int lane = threadIdx.x & 63;
    const int n = blockIdx.x * 4 + (threadIdx.x >> 6);
    const int c = lane * 2;
    const float w00 = wes[c],     w10 = wes[128 + c],     w20 = wes[256 + c],     w30 = wes[384 + c];
    const float w01 = wes[c + 1], w11 = wes[128 + c + 1], w21 = wes[256 + c + 1], w31 = wes[384 + c + 1];

    const int beg = off[n], end = off[n + 1];
    const float2 q2 = *(const float2*)(Q + (size_t)n * HC + c);
    float num0 = 0.f, num1 = 0.f, den = 0.f;

    for (int p = beg; p < end; p++) {
        const int e = eids[p];
        const int src = ei[e];
        const float4 a4 = *(const float4*)(ea + (size_t)e * 4);
        const float e0 = a4.x * w00 + a4.y * w10 + a4.z * w20 + a4.w * w30;
        const float e1 = a4.x * w01 + a4.y * w11 + a4.z * w21 + a4.w * w31;
        const float2 k2 = *(const float2*)(Kp + (size_t)src * HC + c);
        float part = q2.x * (k2.x + e0) + q2.y * (k2.y + e1);
        part += __shfl_xor(part, 1);
        part += __shfl_xor(part, 2);
        part += __shfl_xor(part, 4);
        part += __shfl_xor(part, 8);
        const float al = expf(part * 0.17677669529663687f);  // 1/sqrt(32)
        const float2 v2 = *(const float2*)(V + (size_t)src * HC + c);
        num0 += (v2.x + e0) * al;
        num1 += (v2.y + e1) * al;
        den += al;
    }

    float2* h = (float2*)(H + (size_t)n * HC + c);
    const float2 skip = *h;
    const float inv = 1.f / (den + 1e-16f);
    float o0 = num0 * inv + skip.x;
    float o1 = num1 * inv + skip.y;
    if (do_relu) { o0 = fmaxf(o0, 0.f); o1 = fmaxf(o1, 0.f); }
    *h = make_float2(o0, o1);
}

__global__ __launch_bounds__(256) void pool_scatter(
    const float* __restrict__ h, const int* __restrict__ batch,
    float* __restrict__ pooled, float* __restrict__ cnt)
{
    const int gid = blockIdx.x * 256 + threadIdx.x;
    if (gid >= NN * HC) return;
    const int n = gid >> 7;
    const int hc = gid & 127;
    const int b = batch[n];
    atomicAdd(pooled + (size_t)b * HC + hc, h[gid]);
    if (hc == 0) atomicAdd(cnt + b, 1.0f);
}

__global__ __launch_bounds__(256) void head_k(
    const float* __restrict__ pooled, const float* __restrict__ cnt,
    const int* __restrict__ rt, const float* __restrict__ hW,
    const float* __restrict__ hb, float* __restrict__ out)
{
    const int lane = threadIdx.x & 63;
    const int b = blockIdx.x * 4 + (threadIdx.x >> 6);
    if (b >= BB) return;
    const int t = rt[b];
    const int c = lane * 2;
    const float2 p2 = *(const float2*)(pooled + (size_t)b * HC + c);
    const float2 w2 = *(const float2*)(hW + (size_t)t * HC + c);
    float part = p2.x * w2.x + p2.y * w2.y;
    part += __shfl_xor(part, 1);
    part += __shfl_xor(part, 2);
    part += __shfl_xor(part, 4);
    part += __shfl_xor(part, 8);
    part += __shfl_xor(part, 16);
    part += __shfl_xor(part, 32);
    if (lane == 0) out[b] = part / fmaxf(cnt[b], 1.0f) + hb[t];
}

extern "C" void kernel_launch(void* const* d_in, const int* in_sizes, int n_in,
                              void* d_out, int out_size, void* d_ws, size_t ws_size,
                              hipStream_t stream) {
    const float* x      = (const float*)d_in[0];
    const int*   ei     = (const int*)d_in[1];
    const float* ea     = (const float*)d_in[2];
    const int*   batch  = (const int*)d_in[3];
    const int*   rt     = (const int*)d_in[4];

    // workspace layout (floats/ints) — total ~215 MB
    float* ws     = (float*)d_ws;
    float* Q      = ws;                       // 12,800,000 f
    float* Kp     = ws + 12800000;            // 12,800,000 f
    float* V      = ws + 25600000;            // 12,800,000 f
    float* Hbuf   = ws + 38400000;            // 12,800,000 f (skip + msg = layer output)
    int*   deg    = (int*)(ws + 51200000);    // 100,000 i
    int*   off    = deg + 100000;             // 100,001 i
    int*   cursor = off + 100004;             // 100,000 i
    int*   eids   = cursor + 100000;          // 500,000 i
    int*   bsum   = eids + 500000;            // 128 i
    int*   boff   = bsum + 128;               // 128 i
    float* pooled = (float*)(boff + 128);     // 524,288 f
    float* cnt    = pooled + 524288;          // 4,096 f

    // ---- CSR build (graph identical every call; rebuilt because ws is re-poisoned)
    hipMemsetAsync(deg, 0, 100000 * sizeof(int), stream);
    deg_k<<<(EE + 255) / 256, 256, 0, stream>>>(ei, deg);
    scan_part<<<NSB, 256, 0, stream>>>(deg, bsum);
    scan_top<<<1, 128, 0, stream>>>(bsum, boff);
    scan_final<<<NSB, 256, 0, stream>>>(deg, boff, off, cursor);
    bucket_k<<<(EE + 255) / 256, 256, 0, stream>>>(ei, cursor, eids);

    for (int l = 0; l < 3; l++) {
        const float* in = (l == 0) ? x : Hbuf;
        const int K = (l == 0) ? 64 : 128;
        const float *Wq, *Wk, *Wv, *Wsk, *bq, *bk, *bv, *bs, *We;
        if (l == 0) {
            Wq = (const float*)d_in[5];  bq = (const float*)d_in[6];
            Wk = (const float*)d_in[7];  bk = (const float*)d_in[8];
            Wv = (const float*)d_in[9];  bv = (const float*)d_in[10];
            We = (const float*)d_in[11];
            Wsk= (const float*)d_in[12]; bs = (const float*)d_in[13];
        } else {
            const int j = l - 1;
            Wq = (const float*)d_in[14] + (size_t)j * HC * HC;  bq = (const float*)d_in[15] + j * HC;
            Wk = (const float*)d_in[16] + (size_t)j * HC * HC;  bk = (const float*)d_in[17] + j * HC;
            Wv = (const float*)d_in[18] + (size_t)j * HC * HC;  bv = (const float*)d_in[19] + j * HC;
            We = (const float*)d_in[20] + (size_t)j * 4 * HC;
            Wsk= (const float*)d_in[21] + (size_t)j * HC * HC;  bs = (const float*)d_in[22] + j * HC;
        }

        gemm_all<<<NN / 16, 256, 0, stream>>>(in, K, Wq, Wk, Wv, Wsk, bq, bk, bv, bs,
                                              Q, Kp, V, Hbuf);
        edge_fused<<<NN / 4, 256, 0, stream>>>(ei, ea, We, Q, Kp, V, off, eids,
                                               Hbuf, l < 2 ? 1 : 0);
    }

    hipMemsetAsync(pooled, 0, (size_t)(BB * HC + BB) * sizeof(float), stream);
    pool_scatter<<<(NN * HC) / 256, 256, 0, stream>>>(Hbuf, batch, pooled, cnt);
    head_k<<<BB / 4, 256, 0, stream>>>(pooled, cnt, rt,
        (const float*)d_in[23], (const float*)d_in[24], (float*)d_out);
}

// Round 5
// 1029.483 us; speedup vs baseline: 2.5734x; 1.3655x over previous
//
#include <hip/hip_runtime.h>
#include <hip/hip_bf16.h>

#define NN 100000
#define EE 500000
#define BB 4096
#define HC 128
#define SCAN_ELEM 1024
#define NSB ((NN + SCAN_ELEM - 1) / SCAN_ELEM)   // 98 blocks

typedef __bf16 bf16_t;
typedef bf16_t bf16x8 __attribute__((ext_vector_type(8)));
typedef float f32x4 __attribute__((ext_vector_type(4)));

__device__ __forceinline__ unsigned short f2bf(float f) {
    unsigned u = __builtin_bit_cast(unsigned, f);
    u += 0x7FFFu + ((u >> 16) & 1u);            // RNE
    return (unsigned short)(u >> 16);
}

// ---- convert fp32 -> bf16, 4 elems/thread ----------------------------------
__global__ __launch_bounds__(256) void conv_x(const float* __restrict__ in,
                                              unsigned short* __restrict__ outb,
                                              int total4)
{
    const int g = blockIdx.x * 256 + threadIdx.x;
    if (g >= total4) return;
    const float4 f = *(const float4*)(in + (size_t)g * 4);
    ushort4 u;
    u.x = f2bf(f.x); u.y = f2bf(f.y); u.z = f2bf(f.z); u.w = f2bf(f.w);
    *(ushort4*)(outb + (size_t)g * 4) = u;
}

// ---- convert + transpose weights: W[k,n] fp32 -> Wt[p][n*K+k] bf16 ---------
__global__ __launch_bounds__(256) void prep_w(
    const float* __restrict__ Wq, const float* __restrict__ Wk,
    const float* __restrict__ Wv, const float* __restrict__ Ws,
    unsigned short* __restrict__ Wt, int K)
{
    const int g = blockIdx.x * 256 + threadIdx.x;
    const int per = K * 128;
    if (g >= 4 * per) return;
    const int p = g / per, r = g - p * per;
    const int k = r >> 7, n = r & 127;
    const float* W = p == 0 ? Wq : p == 1 ? Wk : p == 2 ? Wv : Ws;
    Wt[(size_t)p * per + (size_t)n * K + k] = f2bf(W[k * 128 + n]);
}

// ---- MFMA GEMM: out[plane] = A(bf16) @ W(bf16) + b, fp32 out ---------------
// block = 4 waves; wave w does rows rows0..rows0+15, cols w*32..w*32+31.
__global__ __launch_bounds__(256) void gemm_mfma(
    const unsigned short* __restrict__ A, int K,
    const unsigned short* __restrict__ Wt,
    const float* __restrict__ bq, const float* __restrict__ bk,
    const float* __restrict__ bv, const float* __restrict__ bs,
    float* __restrict__ Q, float* __restrict__ Kp,
    float* __restrict__ V, float* __restrict__ S)
{
    const int plane = blockIdx.y;
    const float* bias = plane == 0 ? bq : plane == 1 ? bk : plane == 2 ? bv : bs;
    float* out = plane == 0 ? Q : plane == 1 ? Kp : plane == 2 ? V : S;
    const unsigned short* Wp = Wt + (size_t)plane * 128 * K;

    const int lane = threadIdx.x & 63;
    const int wave = threadIdx.x >> 6;
    const int m = lane & 15, kq = lane >> 4;     // MFMA A/B frag coords
    const int rows0 = blockIdx.x * 16;
    const int col0 = wave * 32;
    const int nkt = K >> 5;                      // K/32 MFMA steps

    bf16x8 a[4];
#pragma unroll
    for (int kt = 0; kt < 4; kt++)
        if (kt < nkt)
            a[kt] = *(const bf16x8*)(A + (size_t)(rows0 + m) * K + kt * 32 + kq * 8);

    f32x4 acc0 = {0.f, 0.f, 0.f, 0.f}, acc1 = {0.f, 0.f, 0.f, 0.f};
#pragma unroll
    for (int kt = 0; kt < 4; kt++) {
        if (kt >= nkt) break;
        const bf16x8 b0 = *(const bf16x8*)(Wp + (size_t)(col0 + m) * K + kt * 32 + kq * 8);
        const bf16x8 b1 = *(const bf16x8*)(Wp + (size_t)(col0 + 16 + m) * K + kt * 32 + kq * 8);
        acc0 = __builtin_amdgcn_mfma_f32_16x16x32_bf16(a[kt], b0, acc0, 0, 0, 0);
        acc1 = __builtin_amdgcn_mfma_f32_16x16x32_bf16(a[kt], b1, acc1, 0, 0, 0);
    }

    const float bi0 = bias[col0 + m];
    const float bi1 = bias[col0 + 16 + m];
    float* o0 = out + (size_t)(rows0 + kq * 4) * HC + col0 + m;   // row=kq*4+r, col=col0+m
#pragma unroll
    for (int r = 0; r < 4; r++) {
        o0[r * HC] = acc0[r] + bi0;
        o0[r * HC + 16] = acc1[r] + bi1;
    }
}

// ---- CSR build: degree histogram -> hierarchical scan -> bucket scatter -----
__global__ __launch_bounds__(256) void deg_k(const int* __restrict__ ei, int* __restrict__ deg)
{
    const int e = blockIdx.x * 256 + threadIdx.x;
    if (e < EE) atomicAdd(&deg[ei[EE + e]], 1);
}

__global__ __launch_bounds__(256) void scan_part(const int* __restrict__ deg,
                                                 int* __restrict__ bsum)
{
    __shared__ int red[256];
    const int base = blockIdx.x * SCAN_ELEM + threadIdx.x * 4;
    int s = 0;
#pragma unroll
    for (int j = 0; j < 4; j++) { const int i = base + j; if (i < NN) s += deg[i]; }
    red[threadIdx.x] = s;
    __syncthreads();
    for (int st = 128; st > 0; st >>= 1) {
        if (threadIdx.x < st) red[threadIdx.x] += red[threadIdx.x + st];
        __syncthreads();
    }
    if (threadIdx.x == 0) bsum[blockIdx.x] = red[0];
}

__global__ __launch_bounds__(128) void scan_top(const int* __restrict__ bsum,
                                                int* __restrict__ boff)
{
    __shared__ int buf[128];
    const int v = (threadIdx.x < NSB) ? bsum[threadIdx.x] : 0;
    buf[threadIdx.x] = v;
    __syncthreads();
    for (int s = 1; s < 128; s <<= 1) {
        const int t = (threadIdx.x >= s) ? buf[threadIdx.x - s] : 0;
        __syncthreads();
        buf[threadIdx.x] += t;
        __syncthreads();
    }
    if (threadIdx.x < NSB) boff[threadIdx.x] = buf[threadIdx.x] - v;
}

__global__ __launch_bounds__(256) void scan_final(const int* __restrict__ deg,
                                                  const int* __restrict__ boff,
                                                  int* __restrict__ off,
                                                  int* __restrict__ cursor)
{
    __shared__ int tsum[256];
    const int base = blockIdx.x * SCAN_ELEM + threadIdx.x * 4;
    int vals[4];
    int s = 0;
#pragma unroll
    for (int j = 0; j < 4; j++) {
        const int i = base + j;
        vals[j] = (i < NN) ? deg[i] : 0;
        s += vals[j];
    }
    tsum[threadIdx.x] = s;
    __syncthreads();
    for (int st = 1; st < 256; st <<= 1) {
        const int t = (threadIdx.x >= st) ? tsum[threadIdx.x - st] : 0;
        __syncthreads();
        tsum[threadIdx.x] += t;
        __syncthreads();
    }
    int ex = boff[blockIdx.x] + tsum[threadIdx.x] - s;
#pragma unroll
    for (int j = 0; j < 4; j++) {
        const int i = base + j;
        if (i < NN) { off[i] = ex; cursor[i] = ex; }
        ex += vals[j];
    }
    if (blockIdx.x == NSB - 1 && threadIdx.x == 255)
        off[NN] = boff[blockIdx.x] + tsum[255];
}

__global__ __launch_bounds__(256) void bucket_k(const int* __restrict__ ei,
                                                int* __restrict__ cursor,
                                                int* __restrict__ eids)
{
    const int e = blockIdx.x * 256 + threadIdx.x;
    if (e < EE) {
        const int d = ei[EE + e];
        const int p = atomicAdd(&cursor[d], 1);
        eids[p] = e;
    }
}

// ---- Fused edge stage: one wave per dst node, gather-based, no atomics. -----
// H holds skip; overwritten with [relu](msg/den + skip). Optionally writes bf16
// copy (next layer's GEMM input).
__global__ __launch_bounds__(256) void edge_fused(
    const int* __restrict__ ei, const float* __restrict__ ea,
    const float* __restrict__ We,
    const float* __restrict__ Q, const float* __restrict__ Kp,
    const float* __restrict__ V,
    const int* __restrict__ off, const int* __restrict__ eids,
    float* __restrict__ H, unsigned short* __restrict__ Hb,
    int do_relu, int wr_bf)
{
    __shared__ float wes[512];
    for (int i = threadIdx.x; i < 512; i += 256) wes[i] = We[i];
    __syncthreads();

    const int lane = threadIdx.x & 63;
    const int n = blockIdx.x * 4 + (threadIdx.x >> 6);
    const int c = lane * 2;
    const float w00 = wes[c],     w10 = wes[128 + c],     w20 = wes[256 + c],     w30 = wes[384 + c];
    const float w01 = wes[c + 1], w11 = wes[128 + c + 1], w21 = wes[256 + c + 1], w31 = wes[384 + c + 1];

    const int beg = off[n], end = off[n + 1];
    const float2 q2 = *(const float2*)(Q + (size_t)n * HC + c);
    float num0 = 0.f, num1 = 0.f, den = 0.f;

    for (int p = beg; p < end; p++) {
        const int e = eids[p];
        const int src = ei[e];
        const float4 a4 = *(const float4*)(ea + (size_t)e * 4);
        const float e0 = a4.x * w00 + a4.y * w10 + a4.z * w20 + a4.w * w30;
        const float e1 = a4.x * w01 + a4.y * w11 + a4.z * w21 + a4.w * w31;
        const float2 k2 = *(const float2*)(Kp + (size_t)src * HC + c);
        float part = q2.x * (k2.x + e0) + q2.y * (k2.y + e1);
        part += __shfl_xor(part, 1);
        part += __shfl_xor(part, 2);
        part += __shfl_xor(part, 4);
        part += __shfl_xor(part, 8);
        const float al = expf(part * 0.17677669529663687f);  // 1/sqrt(32)
        const float2 v2 = *(const float2*)(V + (size_t)src * HC + c);
        num0 += (v2.x + e0) * al;
        num1 += (v2.y + e1) * al;
        den += al;
    }

    float2* h = (float2*)(H + (size_t)n * HC + c);
    const float2 skip = *h;
    const float inv = 1.f / (den + 1e-16f);
    float o0 = num0 * inv + skip.x;
    float o1 = num1 * inv + skip.y;
    if (do_relu) { o0 = fmaxf(o0, 0.f); o1 = fmaxf(o1, 0.f); }
    *h = make_float2(o0, o1);
    if (wr_bf) {
        const unsigned pk = (unsigned)f2bf(o0) | ((unsigned)f2bf(o1) << 16);
        *(unsigned*)(Hb + (size_t)n * HC + c) = pk;
    }
}

__global__ __launch_bounds__(256) void pool_scatter(
    const float* __restrict__ h, const int* __restrict__ batch,
    float* __restrict__ pooled, float* __restrict__ cnt)
{
    const int gid = blockIdx.x * 256 + threadIdx.x;
    if (gid >= NN * HC) return;
    const int n = gid >> 7;
    const int hc = gid & 127;
    const int b = batch[n];
    atomicAdd(pooled + (size_t)b * HC + hc, h[gid]);
    if (hc == 0) atomicAdd(cnt + b, 1.0f);
}

__global__ __launch_bounds__(256) void head_k(
    const float* __restrict__ pooled, const float* __restrict__ cnt,
    const int* __restrict__ rt, const float* __restrict__ hW,
    const float* __restrict__ hb, float* __restrict__ out)
{
    const int lane = threadIdx.x & 63;
    const int b = blockIdx.x * 4 + (threadIdx.x >> 6);
    if (b >= BB) return;
    const int t = rt[b];
    const int c = lane * 2;
    const float2 p2 = *(const float2*)(pooled + (size_t)b * HC + c);
    const float2 w2 = *(const float2*)(hW + (size_t)t * HC + c);
    float part = p2.x * w2.x + p2.y * w2.y;
    part += __shfl_xor(part, 1);
    part += __shfl_xor(part, 2);
    part += __shfl_xor(part, 4);
    part += __shfl_xor(part, 8);
    part += __shfl_xor(part, 16);
    part += __shfl_xor(part, 32);
    if (lane == 0) out[b] = part / fmaxf(cnt[b], 1.0f) + hb[t];
}

extern "C" void kernel_launch(void* const* d_in, const int* in_sizes, int n_in,
                              void* d_out, int out_size, void* d_ws, size_t ws_size,
                              hipStream_t stream) {
    const float* x      = (const float*)d_in[0];
    const int*   ei     = (const int*)d_in[1];
    const float* ea     = (const float*)d_in[2];
    const int*   batch  = (const int*)d_in[3];
    const int*   rt     = (const int*)d_in[4];

    // workspace layout — ~236 MB
    float* ws     = (float*)d_ws;
    float* Q      = ws;                        // 12,800,000 f
    float* Kp     = ws + 12800000;             // 12,800,000 f
    float* V      = ws + 25600000;             // 12,800,000 f
    float* Hbuf   = ws + 38400000;             // 12,800,000 f
    int*   deg    = (int*)(ws + 51200000);     // 100,000 i
    int*   off    = deg + 100000;              // 100,001 i (+pad)
    int*   cursor = off + 100004;              // 100,000 i
    int*   eids   = cursor + 100000;           // 500,000 i
    int*   bsum   = eids + 500000;             // 128 i
    int*   boff   = bsum + 128;                // 128 i
    unsigned short* Abf = (unsigned short*)(boff + 128);  // 12,800,000 us (bf16 GEMM input)
    unsigned short* Wt  = Abf + 12800000;                 // 65,536 us (4 planes, transposed bf16 W)
    float* pooled = (float*)(Wt + 65536);      // 524,288 f
    float* cnt    = pooled + 524288;           // 4,096 f

    // ---- CSR build (graph identical every call; ws re-poisoned each call)
    hipMemsetAsync(deg, 0, 100000 * sizeof(int), stream);
    deg_k<<<(EE + 255) / 256, 256, 0, stream>>>(ei, deg);
    scan_part<<<NSB, 256, 0, stream>>>(deg, bsum);
    scan_top<<<1, 128, 0, stream>>>(bsum, boff);
    scan_final<<<NSB, 256, 0, stream>>>(deg, boff, off, cursor);
    bucket_k<<<(EE + 255) / 256, 256, 0, stream>>>(ei, cursor, eids);

    // layer-1 input -> bf16
    conv_x<<<(NN * 64 / 4 + 255) / 256, 256, 0, stream>>>(x, Abf, NN * 64 / 4);

    for (int l = 0; l < 3; l++) {
        const int K = (l == 0) ? 64 : 128;
        const float *Wq, *Wk, *Wv, *Wsk, *bq, *bk, *bv, *bs, *We;
        if (l == 0) {
            Wq = (const float*)d_in[5];  bq = (const float*)d_in[6];
            Wk = (const float*)d_in[7];  bk = (const float*)d_in[8];
            Wv = (const float*)d_in[9];  bv = (const float*)d_in[10];
            We = (const float*)d_in[11];
            Wsk= (const float*)d_in[12]; bs = (const float*)d_in[13];
        } else {
            const int j = l - 1;
            Wq = (const float*)d_in[14] + (size_t)j * HC * HC;  bq = (const float*)d_in[15] + j * HC;
            Wk = (const float*)d_in[16] + (size_t)j * HC * HC;  bk = (const float*)d_in[17] + j * HC;
            Wv = (const float*)d_in[18] + (size_t)j * HC * HC;  bv = (const float*)d_in[19] + j * HC;
            We = (const float*)d_in[20] + (size_t)j * 4 * HC;
            Wsk= (const float*)d_in[21] + (size_t)j * HC * HC;  bs = (const float*)d_in[22] + j * HC;
        }

        prep_w<<<(4 * K * 128 + 255) / 256, 256, 0, stream>>>(Wq, Wk, Wv, Wsk, Wt, K);
        gemm_mfma<<<dim3(NN / 16, 4), 256, 0, stream>>>(Abf, K, Wt, bq, bk, bv, bs,
                                                        Q, Kp, V, Hbuf);
        edge_fused<<<NN / 4, 256, 0, stream>>>(ei, ea, We, Q, Kp, V, off, eids,
                                               Hbuf, Abf, l < 2 ? 1 : 0, l < 2 ? 1 : 0);
    }

    hipMemsetAsync(pooled, 0, (size_t)(BB * HC + BB) * sizeof(float), stream);
    pool_scatter<<<(NN * HC) / 256, 256, 0, stream>>>(Hbuf, batch, pooled, cnt);
    head_k<<<BB / 4, 256, 0, stream>>>(pooled, cnt, rt,
        (const float*)d_in[23], (const float*)d_in[24], (float*)d_out);
}